// Round 19
// baseline (53.923 us; speedup 1.0000x reference)
//
#include <hip/hip_runtime.h>
#include <hip/hip_bf16.h>
#include <stdint.h>

typedef __attribute__((ext_vector_type(4))) int i32x4;

#define N_ROWS  32768   // 64 * 512
#define N_CODES 1024
#define DIM     512

typedef const __attribute__((address_space(1))) uint32_t guint;
typedef __attribute__((address_space(3))) uint32_t luint;
static __device__ __forceinline__ void gl_lds16(const char* g, char* l) {
    __builtin_amdgcn_global_load_lds((guint*)g, (luint*)l, 16, 0, 0);
}

static __device__ __forceinline__ int q8(float v) {
    int q = __float2int_rn(v * 32.0f);
    return max(-127, min(127, q));
}

// ---------------- K0: quantize X and W to i8 (scale 32) + exact f32 norms ----------------
__global__ void __launch_bounds__(256)
convertXW(const float* __restrict__ X, const float* __restrict__ W,
          char* __restrict__ Xq, char* __restrict__ Wq,
          float* __restrict__ xnorm, float* __restrict__ wnorm) {
    const int lane = threadIdx.x & 63;
    const int sub  = threadIdx.x >> 6;
    const float* src; char* dst; float* nrm; int row;
    if (blockIdx.x < 8192) {
        row = blockIdx.x * 4 + sub;
        src = X; dst = Xq; nrm = xnorm;
    } else {
        row = (blockIdx.x - 8192) * 4 + sub;
        src = W; dst = Wq; nrm = wnorm;
    }
    const float4* p = (const float4*)(src + (size_t)row * DIM + lane * 8);
    float4 a = p[0], b = p[1];
    uint32_t lo = (uint32_t)(q8(a.x) & 0xFF)
                | ((uint32_t)(q8(a.y) & 0xFF) << 8)
                | ((uint32_t)(q8(a.z) & 0xFF) << 16)
                | ((uint32_t)(q8(a.w) & 0xFF) << 24);
    uint32_t hi = (uint32_t)(q8(b.x) & 0xFF)
                | ((uint32_t)(q8(b.y) & 0xFF) << 8)
                | ((uint32_t)(q8(b.z) & 0xFF) << 16)
                | ((uint32_t)(q8(b.w) & 0xFF) << 24);
    *(uint2*)(dst + (size_t)row * DIM + lane * 8) = make_uint2(lo, hi);
    float s = a.x*a.x + a.y*a.y + a.z*a.z + a.w*a.w
            + b.x*b.x + b.y*b.y + b.z*b.z + b.w*b.w;
    #pragma unroll
    for (int d = 1; d < 64; d <<= 1) s += __shfl_xor(s, d);
    if (lane == 0) nrm[row] = s;
}

// ---------------- K1: A-in-REGISTERS, wave-private-B, barrier-free i8 GEMM + argmin ----------------
// Block = 64 rows x ALL 1024 cols; grid 512 (2 blocks/CU; LDS 24KB, VGPR-capped).
// A panel (64x512 i8) lives in 128 VGPRs/lane (aR[m][kt], i32x4), loaded ONCE
// in the prologue directly global->reg: per instr 16 rows x 64B fully-consumed
// lines, L2-hot (XCD row-chunk: XCD x owns rows [x*4096,(x+1)*4096) = 2MB).
// Loop (64 steps = 8 col-subtiles x 8 kt, kt fully unrolled for static aR):
// LDS touched ONLY for B: 2 ds_reads + 2 wave-private gl_lds per step,
// counted vmcnt(2). ZERO barriers before the final merge. B geometry is the
// verified 0-conflict form (64B rows, 4x16B slots, slot XOR (row>>1)&3
// both-sides). Argmin in-block (packed keys, LDS merge); score scale 1/512.
__global__ void __launch_bounds__(256, 2)
gemm_argmin(const char* __restrict__ Xq, const char* __restrict__ Wq,
            const float* __restrict__ wnorm, const float* __restrict__ xnorm,
            float* __restrict__ partial) {
    __shared__ __align__(16) char Bs[4 * 3 * 2048];   // 24 KB: [wave][buf][2KB]

    const int tid  = threadIdx.x;
    const int lane = tid & 63;
    const int wave = tid >> 6;
    const int lr = lane & 15, kg = lane >> 4;

    // XCD row-chunk swizzle: bid = xcd + 8*rl; grid 512.
    const int bid = blockIdx.x;
    const int rowBase = ((bid & 7) * 64 + (bid >> 3)) * 64;
    const int colW = wave * 256;                  // wave's private col swath

    // B staging (verified): rows colW+ct*32+{0..31}, 4 lanes/row, slot
    // pre-swizzled by (row>>1)&3 = (lane>>3)&3; linear gl_lds dest.
    const int ssw = ((lane & 3) ^ ((lane >> 3) & 3)) * 16;
    const char* bS = Wq + (size_t)(colW + (lane >> 2)) * DIM + ssw;
    char* bD = Bs + wave * 6144 + lane * 16;

#define STAGE_B(s) do {                                                       \
    const int ct_ = (s) >> 3, kt_ = (s) & 7, buf_ = (s) % 3;                  \
    gl_lds16(bS + (size_t)(ct_ * 32) * DIM + kt_ * 64,      bD + buf_ * 2048);\
    gl_lds16(bS + (size_t)(ct_ * 32 + 16) * DIM + kt_ * 64, bD + buf_ * 2048 + 1024); \
  } while (0)

    // ---- prologue: A panel -> 128 VGPRs (32 x 16B, L2-hot) + B(0), B(1) ----
    i32x4 aR[4][8];
    {
        const char* aP = Xq + (size_t)(rowBase + lr) * DIM + kg * 16;
        #pragma unroll
        for (int m = 0; m < 4; ++m)
            #pragma unroll
            for (int kt = 0; kt < 8; ++kt)
                aR[m][kt] = *(const i32x4*)(aP + (size_t)(m * 16) * DIM + kt * 64);
    }
    STAGE_B(0);
    STAGE_B(1);
    asm volatile("s_waitcnt vmcnt(2)" ::: "memory");   // A + B(0) landed

    i32x4 acc[4][2];
    #pragma unroll
    for (int m = 0; m < 4; ++m) { acc[m][0] = (i32x4)0; acc[m][1] = (i32x4)0; }
    uint32_t runKey[4][4];
    #pragma unroll
    for (int m = 0; m < 4; ++m)
        #pragma unroll
        for (int r = 0; r < 4; ++r) runKey[m][r] = 0xFFFFFFFFu;

    const int fq = (kg ^ ((lr >> 1) & 3)) * 16;   // B swizzled read slot
    const char* bR = Bs + wave * 6144;

    for (int ct = 0; ct < 8; ++ct) {
        #pragma unroll
        for (int kt = 0; kt < 8; ++kt) {
            const int s = ct * 8 + kt;
            const int buf = s % 3;
            i32x4 bF[2];
            #pragma unroll
            for (int n = 0; n < 2; ++n)
                bF[n] = *(const i32x4*)&bR[buf * 2048 + (n * 16 + lr) * 64 + fq];
            if (s + 2 < 64) STAGE_B(s + 2);       // depth-2, wave-private
            #pragma unroll
            for (int m = 0; m < 4; ++m)
                #pragma unroll
                for (int n = 0; n < 2; ++n)
                    acc[m][n] = __builtin_amdgcn_mfma_i32_16x16x64_i8(
                        aR[m][kt], bF[n], acc[m][n], 0, 0, 0);
            if (s + 2 < 64)   asm volatile("s_waitcnt vmcnt(2)" ::: "memory");
            else if (s == 62) asm volatile("s_waitcnt vmcnt(0)" ::: "memory");
        }
        // col-subtile complete: fold scores into running packed keys
        #pragma unroll
        for (int n = 0; n < 2; ++n) {
            const int wcol = colW + ct * 32 + n * 16 + lr;
            const float wn = wnorm[wcol];
            #pragma unroll
            for (int m = 0; m < 4; ++m)
                #pragma unroll
                for (int r = 0; r < 4; ++r) {
                    float sc = wn - (float)acc[m][n][r] * 0.001953125f;
                    uint32_t u = __float_as_uint(sc);
                    u = (u & 0x80000000u) ? ~u : (u | 0x80000000u);
                    runKey[m][r] = min(runKey[m][r],
                                       (u & ~1023u) | (uint32_t)wcol);
                }
        }
        #pragma unroll
        for (int m = 0; m < 4; ++m) { acc[m][0] = (i32x4)0; acc[m][1] = (i32x4)0; }
    }
#undef STAGE_B

    // ---- per-wave 16-lane col reduce, write per-row keys into OWN B region ----
    uint32_t* kbuf = (uint32_t*)(Bs + wave * 6144);   // own region, loop done
    #pragma unroll
    for (int m = 0; m < 4; ++m)
        #pragma unroll
        for (int r = 0; r < 4; ++r) {
            uint32_t k = runKey[m][r];
            #pragma unroll
            for (int d = 1; d < 16; d <<= 1)
                k = min(k, (uint32_t)__shfl_xor((int)k, d));
            if (lr == 0) kbuf[m * 16 + kg * 4 + r] = k;
        }
    __syncthreads();

    // ---- wave 0: merge 4 waves' keys per row, add xnorm, block sum ----
    if (wave == 0) {
        const uint32_t* k0 = (const uint32_t*)(Bs);
        uint32_t k = min(min(k0[lane], k0[1536 + lane]),
                         min(k0[3072 + lane], k0[4608 + lane]));
        uint32_t sb = k & ~1023u;
        float sc = (sb & 0x80000000u) ? __uint_as_float(sb ^ 0x80000000u)
                                      : __uint_as_float(~sb);
        float v = xnorm[rowBase + lane] + sc;
        #pragma unroll
        for (int d = 1; d < 64; d <<= 1) v += __shfl_xor(v, d);
        if (lane == 0) partial[bid] = v;
    }
}

// ---------------- K2: final mean over 512 partials (double accum) ----------------
__global__ void __launch_bounds__(256)
finalize(const float* __restrict__ partial, float* __restrict__ out) {
    __shared__ double sm[256];
    sm[threadIdx.x] = (double)partial[threadIdx.x]
                    + (double)partial[threadIdx.x + 256];
    __syncthreads();
    for (int st = 128; st > 0; st >>= 1) {
        if (threadIdx.x < st) sm[threadIdx.x] += sm[threadIdx.x + st];
        __syncthreads();
    }
    if (threadIdx.x == 0)
        out[0] = (float)(sm[0] / (double)((size_t)N_ROWS * DIM));
}

extern "C" void kernel_launch(void* const* d_in, const int* in_sizes, int n_in,
                              void* d_out, int out_size, void* d_ws, size_t ws_size,
                              hipStream_t stream) {
    const float* X = (const float*)d_in[0];   // [32768][512]
    const float* W = (const float*)d_in[1];   // [1024][512]
    char* ws = (char*)d_ws;
    char*   Xq      = ws;                                  // 16 MB @ 0
    char*   Wq      = ws + 16777216;                       // 512 KB
    float*  wnorm   = (float*)(ws + 17301504);             // 4 KB
    float*  xnorm   = (float*)(ws + 17305600);             // 128 KB
    float*  partial = (float*)(ws + 17436672);             // 2 KB
    float*  out     = (float*)d_out;

    convertXW<<<8192 + N_CODES / 4, 256, 0, stream>>>(X, W, Xq, Wq, xnorm, wnorm);
    gemm_argmin<<<512, 256, 0, stream>>>(Xq, Wq, wnorm, xnorm, partial);
    finalize<<<1, 256, 0, stream>>>(partial, out);
}

// Round 20
// 53.262 us; speedup vs baseline: 1.0124x; 1.0124x over previous
//
#include <hip/hip_runtime.h>
#include <hip/hip_bf16.h>
#include <stdint.h>

typedef __attribute__((ext_vector_type(4))) int i32x4;

#define N_ROWS  32768   // 64 * 512
#define N_CODES 1024
#define DIM     512

typedef const __attribute__((address_space(1))) uint32_t guint;
typedef __attribute__((address_space(3))) uint32_t luint;
static __device__ __forceinline__ void gl_lds16(const char* g, char* l) {
    __builtin_amdgcn_global_load_lds((guint*)g, (luint*)l, 16, 0, 0);
}

static __device__ __forceinline__ int q8(float v) {
    int q = __float2int_rn(v * 32.0f);
    return max(-127, min(127, q));
}

// ---------------- K0: quantize X and W to i8 (scale 32) + exact f32 norms ----------------
__global__ void __launch_bounds__(256)
convertXW(const float* __restrict__ X, const float* __restrict__ W,
          char* __restrict__ Xq, char* __restrict__ Wq,
          float* __restrict__ xnorm, float* __restrict__ wnorm) {
    const int lane = threadIdx.x & 63;
    const int sub  = threadIdx.x >> 6;
    const float* src; char* dst; float* nrm; int row;
    if (blockIdx.x < 8192) {
        row = blockIdx.x * 4 + sub;
        src = X; dst = Xq; nrm = xnorm;
    } else {
        row = (blockIdx.x - 8192) * 4 + sub;
        src = W; dst = Wq; nrm = wnorm;
    }
    const float4* p = (const float4*)(src + (size_t)row * DIM + lane * 8);
    float4 a = p[0], b = p[1];
    uint32_t lo = (uint32_t)(q8(a.x) & 0xFF)
                | ((uint32_t)(q8(a.y) & 0xFF) << 8)
                | ((uint32_t)(q8(a.z) & 0xFF) << 16)
                | ((uint32_t)(q8(a.w) & 0xFF) << 24);
    uint32_t hi = (uint32_t)(q8(b.x) & 0xFF)
                | ((uint32_t)(q8(b.y) & 0xFF) << 8)
                | ((uint32_t)(q8(b.z) & 0xFF) << 16)
                | ((uint32_t)(q8(b.w) & 0xFF) << 24);
    *(uint2*)(dst + (size_t)row * DIM + lane * 8) = make_uint2(lo, hi);
    float s = a.x*a.x + a.y*a.y + a.z*a.z + a.w*a.w
            + b.x*b.x + b.y*b.y + b.z*b.z + b.w*b.w;
    #pragma unroll
    for (int d = 1; d < 64; d <<= 1) s += __shfl_xor(s, d);
    if (lane == 0) nrm[row] = s;
}

// ---------------- K1: A-in-REGISTERS (pinned), wave-private-B, barrier-free i8 GEMM ----------------
// R19 retry with FORCED residency: after the prologue global->reg A loads,
// each aR[m][kt] is pinned via asm volatile("" : "+v") -- loads must complete
// before the asm and the loop consumes the asm's opaque result, so the
// compiler cannot sink/rematerialize them (R19's failure: VGPR=104 proved it
// re-loaded A per iteration, serializing the counted vmcnt gates).
// __launch_bounds__(256,2) -> 256-VGPR budget; aR(128)+acc(32)+keys(16)+misc
// fits ~226. LDS = B-only 24KB; 2 blocks/CU. In-loop LDS: 2 ds_reads +
// 2 wave-private gl_lds per 8 MFMA -> matrix pipe finally dominant.
// All other pieces verified: B 0-conflict geometry (slot XOR (row>>1)&3
// both-sides), counted vmcnt(2), XCD row-chunk, packed-key argmin in-block.
__global__ void __launch_bounds__(256, 2)
gemm_argmin(const char* __restrict__ Xq, const char* __restrict__ Wq,
            const float* __restrict__ wnorm, const float* __restrict__ xnorm,
            float* __restrict__ partial) {
    __shared__ __align__(16) char Bs[4 * 3 * 2048];   // 24 KB: [wave][buf][2KB]

    const int tid  = threadIdx.x;
    const int lane = tid & 63;
    const int wave = tid >> 6;
    const int lr = lane & 15, kg = lane >> 4;

    // XCD row-chunk swizzle: bid = xcd + 8*rl; grid 512.
    const int bid = blockIdx.x;
    const int rowBase = ((bid & 7) * 64 + (bid >> 3)) * 64;
    const int colW = wave * 256;                  // wave's private col swath

    const int ssw = ((lane & 3) ^ ((lane >> 3) & 3)) * 16;
    const char* bS = Wq + (size_t)(colW + (lane >> 2)) * DIM + ssw;
    char* bD = Bs + wave * 6144 + lane * 16;

#define STAGE_B(s) do {                                                       \
    const int ct_ = (s) >> 3, kt_ = (s) & 7, buf_ = (s) % 3;                  \
    gl_lds16(bS + (size_t)(ct_ * 32) * DIM + kt_ * 64,      bD + buf_ * 2048);\
    gl_lds16(bS + (size_t)(ct_ * 32 + 16) * DIM + kt_ * 64, bD + buf_ * 2048 + 1024); \
  } while (0)

    // ---- prologue: A panel -> 128 VGPRs, PINNED; then B(0), B(1) ----
    i32x4 aR[4][8];
    {
        const char* aP = Xq + (size_t)(rowBase + lr) * DIM + kg * 16;
        #pragma unroll
        for (int m = 0; m < 4; ++m)
            #pragma unroll
            for (int kt = 0; kt < 8; ++kt)
                aR[m][kt] = *(const i32x4*)(aP + (size_t)(m * 16) * DIM + kt * 64);
    }
    #pragma unroll
    for (int m = 0; m < 4; ++m)
        #pragma unroll
        for (int kt = 0; kt < 8; ++kt)
            asm volatile("" : "+v"(aR[m][kt]));   // force residency (rule #17)
    STAGE_B(0);
    STAGE_B(1);
    asm volatile("s_waitcnt vmcnt(2)" ::: "memory");   // A + B(0) landed

    i32x4 acc[4][2];
    #pragma unroll
    for (int m = 0; m < 4; ++m) { acc[m][0] = (i32x4)0; acc[m][1] = (i32x4)0; }
    uint32_t runKey[4][4];
    #pragma unroll
    for (int m = 0; m < 4; ++m)
        #pragma unroll
        for (int r = 0; r < 4; ++r) runKey[m][r] = 0xFFFFFFFFu;

    const int fq = (kg ^ ((lr >> 1) & 3)) * 16;   // B swizzled read slot
    const char* bR = Bs + wave * 6144;

    for (int ct = 0; ct < 8; ++ct) {
        #pragma unroll
        for (int kt = 0; kt < 8; ++kt) {
            const int s = ct * 8 + kt;
            const int buf = s % 3;
            i32x4 bF[2];
            #pragma unroll
            for (int n = 0; n < 2; ++n)
                bF[n] = *(const i32x4*)&bR[buf * 2048 + (n * 16 + lr) * 64 + fq];
            if (s + 2 < 64) STAGE_B(s + 2);       // depth-2, wave-private
            #pragma unroll
            for (int m = 0; m < 4; ++m)
                #pragma unroll
                for (int n = 0; n < 2; ++n)
                    acc[m][n] = __builtin_amdgcn_mfma_i32_16x16x64_i8(
                        aR[m][kt], bF[n], acc[m][n], 0, 0, 0);
            if (s + 2 < 64)   asm volatile("s_waitcnt vmcnt(2)" ::: "memory");
            else if (s == 62) asm volatile("s_waitcnt vmcnt(0)" ::: "memory");
        }
        // col-subtile complete: fold scores into running packed keys
        #pragma unroll
        for (int n = 0; n < 2; ++n) {
            const int wcol = colW + ct * 32 + n * 16 + lr;
            const float wn = wnorm[wcol];
            #pragma unroll
            for (int m = 0; m < 4; ++m)
                #pragma unroll
                for (int r = 0; r < 4; ++r) {
                    float sc = wn - (float)acc[m][n][r] * 0.001953125f;
                    uint32_t u = __float_as_uint(sc);
                    u = (u & 0x80000000u) ? ~u : (u | 0x80000000u);
                    runKey[m][r] = min(runKey[m][r],
                                       (u & ~1023u) | (uint32_t)wcol);
                }
        }
        #pragma unroll
        for (int m = 0; m < 4; ++m) { acc[m][0] = (i32x4)0; acc[m][1] = (i32x4)0; }
    }
#undef STAGE_B

    // ---- per-wave 16-lane col reduce, write per-row keys into OWN B region ----
    uint32_t* kbuf = (uint32_t*)(Bs + wave * 6144);   // own region, loop done
    #pragma unroll
    for (int m = 0; m < 4; ++m)
        #pragma unroll
        for (int r = 0; r < 4; ++r) {
            uint32_t k = runKey[m][r];
            #pragma unroll
            for (int d = 1; d < 16; d <<= 1)
                k = min(k, (uint32_t)__shfl_xor((int)k, d));
            if (lr == 0) kbuf[m * 16 + kg * 4 + r] = k;
        }
    __syncthreads();

    // ---- wave 0: merge 4 waves' keys per row, add xnorm, block sum ----
    if (wave == 0) {
        const uint32_t* k0 = (const uint32_t*)(Bs);
        uint32_t k = min(min(k0[lane], k0[1536 + lane]),
                         min(k0[3072 + lane], k0[4608 + lane]));
        uint32_t sb = k & ~1023u;
        float sc = (sb & 0x80000000u) ? __uint_as_float(sb ^ 0x80000000u)
                                      : __uint_as_float(~sb);
        float v = xnorm[rowBase + lane] + sc;
        #pragma unroll
        for (int d = 1; d < 64; d <<= 1) v += __shfl_xor(v, d);
        if (lane == 0) partial[bid] = v;
    }
}

// ---------------- K2: final mean over 512 partials (double accum) ----------------
__global__ void __launch_bounds__(256)
finalize(const float* __restrict__ partial, float* __restrict__ out) {
    __shared__ double sm[256];
    sm[threadIdx.x] = (double)partial[threadIdx.x]
                    + (double)partial[threadIdx.x + 256];
    __syncthreads();
    for (int st = 128; st > 0; st >>= 1) {
        if (threadIdx.x < st) sm[threadIdx.x] += sm[threadIdx.x + st];
        __syncthreads();
    }
    if (threadIdx.x == 0)
        out[0] = (float)(sm[0] / (double)((size_t)N_ROWS * DIM));
}

extern "C" void kernel_launch(void* const* d_in, const int* in_sizes, int n_in,
                              void* d_out, int out_size, void* d_ws, size_t ws_size,
                              hipStream_t stream) {
    const float* X = (const float*)d_in[0];   // [32768][512]
    const float* W = (const float*)d_in[1];   // [1024][512]
    char* ws = (char*)d_ws;
    char*   Xq      = ws;                                  // 16 MB @ 0
    char*   Wq      = ws + 16777216;                       // 512 KB
    float*  wnorm   = (float*)(ws + 17301504);             // 4 KB
    float*  xnorm   = (float*)(ws + 17305600);             // 128 KB
    float*  partial = (float*)(ws + 17436672);             // 2 KB
    float*  out     = (float*)d_out;

    convertXW<<<8192 + N_CODES / 4, 256, 0, stream>>>(X, W, Xq, Wq, xnorm, wnorm);
    gemm_argmin<<<512, 256, 0, stream>>>(Xq, Wq, wnorm, xnorm, partial);
    finalize<<<1, 256, 0, stream>>>(partial, out);
}

// Round 21
// 48.557 us; speedup vs baseline: 1.1105x; 1.0969x over previous
//
#include <hip/hip_runtime.h>
#include <hip/hip_bf16.h>
#include <stdint.h>

typedef __attribute__((ext_vector_type(4))) int i32x4;

#define N_ROWS  32768   // 64 * 512
#define N_CODES 1024
#define DIM     512

typedef const __attribute__((address_space(1))) uint32_t guint;
typedef __attribute__((address_space(3))) uint32_t luint;
static __device__ __forceinline__ void gl_lds16(const char* g, char* l) {
    __builtin_amdgcn_global_load_lds((guint*)g, (luint*)l, 16, 0, 0);
}

static __device__ __forceinline__ int q8(float v) {
    int q = __float2int_rn(v * 32.0f);
    return max(-127, min(127, q));
}

// ---------------- K0: quantize X and W to i8 (scale 32) + exact f32 norms ----------------
__global__ void __launch_bounds__(256)
convertXW(const float* __restrict__ X, const float* __restrict__ W,
          char* __restrict__ Xq, char* __restrict__ Wq,
          float* __restrict__ xnorm, float* __restrict__ wnorm) {
    const int lane = threadIdx.x & 63;
    const int sub  = threadIdx.x >> 6;
    const float* src; char* dst; float* nrm; int row;
    if (blockIdx.x < 8192) {
        row = blockIdx.x * 4 + sub;
        src = X; dst = Xq; nrm = xnorm;
    } else {
        row = (blockIdx.x - 8192) * 4 + sub;
        src = W; dst = Wq; nrm = wnorm;
    }
    const float4* p = (const float4*)(src + (size_t)row * DIM + lane * 8);
    float4 a = p[0], b = p[1];
    uint32_t lo = (uint32_t)(q8(a.x) & 0xFF)
                | ((uint32_t)(q8(a.y) & 0xFF) << 8)
                | ((uint32_t)(q8(a.z) & 0xFF) << 16)
                | ((uint32_t)(q8(a.w) & 0xFF) << 24);
    uint32_t hi = (uint32_t)(q8(b.x) & 0xFF)
                | ((uint32_t)(q8(b.y) & 0xFF) << 8)
                | ((uint32_t)(q8(b.z) & 0xFF) << 16)
                | ((uint32_t)(q8(b.w) & 0xFF) << 24);
    *(uint2*)(dst + (size_t)row * DIM + lane * 8) = make_uint2(lo, hi);
    float s = a.x*a.x + a.y*a.y + a.z*a.z + a.w*a.w
            + b.x*b.x + b.y*b.y + b.z*b.z + b.w*b.w;
    #pragma unroll
    for (int d = 1; d < 64; d <<= 1) s += __shfl_xor(s, d);
    if (lane == 0) nrm[row] = s;
}

// ---------------- K1: A-resident, wave-private-B, ct-PAIR barrier-free i8 GEMM + argmin ----------------
// R18 (50.4us champion) + ct-pair processing: each step covers a 64-col pair
// of subtiles -> 4 B-frags x 4 A-frags = 16 MFMA per {4 A-reads + 4 B-reads
// + 4 DMA writes} -> LDS cost 10.5 -> 7.5 cy/MFMA (-29% on the dominant
// pipe); A-frag reuse 2x -> 4x. LDS: A 32KB + B 4w x 3buf x 4KB = 80KB ->
// exactly 2 blocks/CU. Zero barriers in the 32-step loop (wave-private B,
// counted vmcnt(4), depth-2). All geometry verified-0-conflict: A segments
// As[kt][64][64] + slot XOR (row>>1)&3 both-sides; B same form, 64-row bufs.
// XCD row-chunk: XCD x owns rows [x*4096,(x+1)*4096) = 2MB Xq (L2-resident).
__global__ void __launch_bounds__(256, 2)
gemm_argmin(const char* __restrict__ Xq, const char* __restrict__ Wq,
            const float* __restrict__ wnorm, const float* __restrict__ xnorm,
            float* __restrict__ partial) {
    __shared__ __align__(16) char As[8 * 4096];        // 32 KB: [kt][row][slot]
    __shared__ __align__(16) char Bs[4 * 3 * 4096];    // 48 KB: [wave][buf][4KB]

    const int tid  = threadIdx.x;
    const int lane = tid & 63;
    const int wave = tid >> 6;
    const int lr = lane & 15, kg = lane >> 4;

    // XCD row-chunk swizzle: bid = xcd + 8*rl; grid 512.
    const int bid = blockIdx.x;
    const int rowBase = ((bid & 7) * 64 + (bid >> 3)) * 64;
    const int colW = wave * 256;                  // wave's private col swath

    // verified slot pre-swizzle: src slot (lane&3) ^ ((row>>1)&3)
    const int ssw = ((lane & 3) ^ ((lane >> 3) & 3)) * 16;
    const char* aS = Xq + (size_t)(rowBase + wave * 16 + (lane >> 2)) * DIM + ssw;
    const char* bS = Wq + (size_t)(colW + (lane >> 2)) * DIM + ssw;
    char* bD = Bs + wave * 12288 + lane * 16;

    // stage step s (s = ctp*8 + kt): 64 rows (ct-pair) x 64B k-slice, 4 instrs
#define STAGE_B(s) do {                                                       \
    const int ctp_ = (s) >> 3, kt_ = (s) & 7, buf_ = (s) % 3;                 \
    _Pragma("unroll")                                                         \
    for (int j = 0; j < 4; ++j)                                               \
        gl_lds16(bS + (size_t)(ctp_ * 64 + j * 16) * DIM + kt_ * 64,          \
                 bD + buf_ * 4096 + j * 1024);                                \
  } while (0)

    // ---- prologue: resident A (8 segments, 8 loads) + B(0), B(1) ----
    #pragma unroll
    for (int kt = 0; kt < 8; ++kt)
        gl_lds16(aS + kt * 64, As + kt * 4096 + wave * 1024 + lane * 16);
    STAGE_B(0);
    STAGE_B(1);
    asm volatile("s_waitcnt vmcnt(4)" ::: "memory");   // A + B(0) landed
    __syncthreads();                                   // A visible to all waves

    i32x4 acc[4][4];
    #pragma unroll
    for (int m = 0; m < 4; ++m)
        #pragma unroll
        for (int n = 0; n < 4; ++n) acc[m][n] = (i32x4)0;
    uint32_t runKey[4][4];
    #pragma unroll
    for (int m = 0; m < 4; ++m)
        #pragma unroll
        for (int r = 0; r < 4; ++r) runKey[m][r] = 0xFFFFFFFFu;

    const int fq = (kg ^ ((lr >> 1) & 3)) * 16;   // swizzled read slot (bytes)
    const char* bR = Bs + wave * 12288;

    for (int ctp = 0; ctp < 4; ++ctp) {
        #pragma unroll
        for (int kt = 0; kt < 8; ++kt) {
            const int s = ctp * 8 + kt;
            const int buf = s % 3;
            i32x4 aF[4], bF[4];
            #pragma unroll
            for (int m = 0; m < 4; ++m)
                aF[m] = *(const i32x4*)&As[kt * 4096 + (m * 16 + lr) * 64 + fq];
            #pragma unroll
            for (int n = 0; n < 4; ++n)
                bF[n] = *(const i32x4*)&bR[buf * 4096 + (n * 16 + lr) * 64 + fq];
            if (s + 2 < 32) STAGE_B(s + 2);       // depth-2, wave-private
            #pragma unroll
            for (int m = 0; m < 4; ++m)
                #pragma unroll
                for (int n = 0; n < 4; ++n)
                    acc[m][n] = __builtin_amdgcn_mfma_i32_16x16x64_i8(
                        aF[m], bF[n], acc[m][n], 0, 0, 0);
            if (s + 2 < 32)   asm volatile("s_waitcnt vmcnt(4)" ::: "memory");
            else if (s == 30) asm volatile("s_waitcnt vmcnt(0)" ::: "memory");
        }
        // ct-pair complete: fold scores into running packed keys
        #pragma unroll
        for (int n = 0; n < 4; ++n) {
            const int wcol = colW + ctp * 64 + n * 16 + lr;
            const float wn = wnorm[wcol];
            #pragma unroll
            for (int m = 0; m < 4; ++m)
                #pragma unroll
                for (int r = 0; r < 4; ++r) {
                    float sc = wn - (float)acc[m][n][r] * 0.001953125f;
                    uint32_t u = __float_as_uint(sc);
                    u = (u & 0x80000000u) ? ~u : (u | 0x80000000u);
                    runKey[m][r] = min(runKey[m][r],
                                       (u & ~1023u) | (uint32_t)wcol);
                }
        }
        #pragma unroll
        for (int m = 0; m < 4; ++m)
            #pragma unroll
            for (int n = 0; n < 4; ++n) acc[m][n] = (i32x4)0;
    }
#undef STAGE_B

    // ---- per-wave 16-lane col reduce, write per-row keys into OWN B region ----
    uint32_t* kbuf = (uint32_t*)(Bs + wave * 12288);   // own region, loop done
    #pragma unroll
    for (int m = 0; m < 4; ++m)
        #pragma unroll
        for (int r = 0; r < 4; ++r) {
            uint32_t k = runKey[m][r];
            #pragma unroll
            for (int d = 1; d < 16; d <<= 1)
                k = min(k, (uint32_t)__shfl_xor((int)k, d));
            if (lr == 0) kbuf[m * 16 + kg * 4 + r] = k;
        }
    __syncthreads();

    // ---- wave 0: merge 4 waves' keys per row, add xnorm, block sum ----
    if (wave == 0) {
        const uint32_t* k0 = (const uint32_t*)(Bs);
        uint32_t k = min(min(k0[lane], k0[3072 + lane]),
                         min(k0[6144 + lane], k0[9216 + lane]));
        uint32_t sb = k & ~1023u;
        float sc = (sb & 0x80000000u) ? __uint_as_float(sb ^ 0x80000000u)
                                      : __uint_as_float(~sb);
        float v = xnorm[rowBase + lane] + sc;
        #pragma unroll
        for (int d = 1; d < 64; d <<= 1) v += __shfl_xor(v, d);
        if (lane == 0) partial[bid] = v;
    }
}

// ---------------- K2: final mean over 512 partials (double accum) ----------------
__global__ void __launch_bounds__(256)
finalize(const float* __restrict__ partial, float* __restrict__ out) {
    __shared__ double sm[256];
    sm[threadIdx.x] = (double)partial[threadIdx.x]
                    + (double)partial[threadIdx.x + 256];
    __syncthreads();
    for (int st = 128; st > 0; st >>= 1) {
        if (threadIdx.x < st) sm[threadIdx.x] += sm[threadIdx.x + st];
        __syncthreads();
    }
    if (threadIdx.x == 0)
        out[0] = (float)(sm[0] / (double)((size_t)N_ROWS * DIM));
}

extern "C" void kernel_launch(void* const* d_in, const int* in_sizes, int n_in,
                              void* d_out, int out_size, void* d_ws, size_t ws_size,
                              hipStream_t stream) {
    const float* X = (const float*)d_in[0];   // [32768][512]
    const float* W = (const float*)d_in[1];   // [1024][512]
    char* ws = (char*)d_ws;
    char*   Xq      = ws;                                  // 16 MB @ 0
    char*   Wq      = ws + 16777216;                       // 512 KB
    float*  wnorm   = (float*)(ws + 17301504);             // 4 KB
    float*  xnorm   = (float*)(ws + 17305600);             // 128 KB
    float*  partial = (float*)(ws + 17436672);             // 2 KB
    float*  out     = (float*)d_out;

    convertXW<<<8192 + N_CODES / 4, 256, 0, stream>>>(X, W, Xq, Wq, xnorm, wnorm);
    gemm_argmin<<<512, 256, 0, stream>>>(Xq, Wq, wnorm, xnorm, partial);
    finalize<<<1, 256, 0, stream>>>(partial, out);
}

// Round 22
// 47.400 us; speedup vs baseline: 1.1376x; 1.0244x over previous
//
#include <hip/hip_runtime.h>
#include <hip/hip_bf16.h>
#include <stdint.h>

typedef __attribute__((ext_vector_type(4))) int i32x4;

#define N_ROWS  32768   // 64 * 512
#define N_CODES 1024
#define DIM     512

typedef const __attribute__((address_space(1))) uint32_t guint;
typedef __attribute__((address_space(3))) uint32_t luint;
static __device__ __forceinline__ void gl_lds16(const char* g, char* l) {
    __builtin_amdgcn_global_load_lds((guint*)g, (luint*)l, 16, 0, 0);
}

static __device__ __forceinline__ int q8(float v) {
    int q = __float2int_rn(v * 32.0f);
    return max(-127, min(127, q));
}
static __device__ __forceinline__ uint32_t pack4(float a, float b, float c, float d) {
    return (uint32_t)(q8(a) & 0xFF) | ((uint32_t)(q8(b) & 0xFF) << 8)
         | ((uint32_t)(q8(c) & 0xFF) << 16) | ((uint32_t)(q8(d) & 0xFF) << 24);
}

// ---------------- K0: quantize W to i8 (scale 32) + exact f32 norms ----------------
__global__ void __launch_bounds__(256)
convertW(const float* __restrict__ W, char* __restrict__ Wq,
         float* __restrict__ wnorm) {
    const int lane = threadIdx.x & 63;
    const int code = blockIdx.x * 4 + (threadIdx.x >> 6);
    const float4* p = (const float4*)(W + (size_t)code * DIM + lane * 8);
    float4 a = p[0], b = p[1];
    *(uint2*)(Wq + (size_t)code * DIM + lane * 8) =
        make_uint2(pack4(a.x, a.y, a.z, a.w), pack4(b.x, b.y, b.z, b.w));
    float s = a.x*a.x + a.y*a.y + a.z*a.z + a.w*a.w
            + b.x*b.x + b.y*b.y + b.z*b.z + b.w*b.w;
    #pragma unroll
    for (int d = 1; d < 64; d <<= 1) s += __shfl_xor(s, d);
    if (lane == 0) wnorm[code] = s;
}

// ---------------- K1: fused X-quantize + A-resident ct-pair barrier-free i8 GEMM ----------------
// R21 (48.6us champion) + X-conversion fused into the prologue: each block
// owns a 64-row strip exclusively, reads it ONCE as f32 (4 threads/row,
// full-line utilization via L1), computes EXACT f32 xnorm in-register,
// quantizes to i8 and ds_writes into the SAME resident As layout the loop
// reads (As[kt][row][slot], phys slot = sl ^ ((row>>1)&3)). Eliminates Xq,
// the 16MB write+re-read, the xnorm array, and the X half of convertXW.
// Loop byte-identical to R21: ct-pair (16 MFMA per 8 LDS reads + 4 DMA),
// wave-private 3x4KB B bufs, counted vmcnt(4), zero barriers, verified
// 0-conflict geometry, XCD row-chunk (bid = xcd + 8*rl). LDS = exactly 80KB
// -> 2 blocks/CU. xnorm rides a VGPR through the loop, parked in dead Bs
// space for the merge.
__global__ void __launch_bounds__(256, 2)
gemm_argmin(const float* __restrict__ X, const char* __restrict__ Wq,
            const float* __restrict__ wnorm, float* __restrict__ partial) {
    __shared__ __align__(16) char As[8 * 4096];        // 32 KB: [kt][row][slot]
    __shared__ __align__(16) char Bs[4 * 3 * 4096];    // 48 KB: [wave][buf][4KB]

    const int tid  = threadIdx.x;
    const int lane = tid & 63;
    const int wave = tid >> 6;
    const int lr = lane & 15, kg = lane >> 4;

    // XCD row-chunk swizzle: bid = xcd + 8*rl; grid 512.
    const int bid = blockIdx.x;
    const int rowBase = ((bid & 7) * 64 + (bid >> 3)) * 64;
    const int colW = wave * 256;                  // wave's private col swath

    // B staging (verified 0-conflict): slot pre-swizzled by (row>>1)&3.
    const int ssw = ((lane & 3) ^ ((lane >> 3) & 3)) * 16;
    const char* bS = Wq + (size_t)(colW + (lane >> 2)) * DIM + ssw;
    char* bD = Bs + wave * 12288 + lane * 16;

#define STAGE_B(s) do {                                                       \
    const int ctp_ = (s) >> 3, kt_ = (s) & 7, buf_ = (s) % 3;                 \
    _Pragma("unroll")                                                         \
    for (int j = 0; j < 4; ++j)                                               \
        gl_lds16(bS + (size_t)(ctp_ * 64 + j * 16) * DIM + kt_ * 64,          \
                 bD + buf_ * 4096 + j * 1024);                                \
  } while (0)

    // ---- issue B(0), B(1) first: they land under the long f32 prologue ----
    STAGE_B(0);
    STAGE_B(1);

    // ---- prologue: f32 X strip -> exact xnorm + i8 into resident As ----
    // thread t: row r = t>>2, quarter q4 = t&3 (128 elements = kt pair).
    const int r = tid >> 2, q4 = tid & 3;
    const int rsw = (r >> 1) & 3;                 // row's slot XOR
    float nrm = 0.f;
    {
        const float* xP = X + (size_t)(rowBase + r) * DIM + q4 * 128;
        #pragma unroll
        for (int c = 0; c < 8; ++c) {             // 8 chunks of 16 elements
            float4 f0 = *(const float4*)(xP + c * 16);
            float4 f1 = *(const float4*)(xP + c * 16 + 4);
            float4 f2 = *(const float4*)(xP + c * 16 + 8);
            float4 f3 = *(const float4*)(xP + c * 16 + 12);
            nrm += f0.x*f0.x + f0.y*f0.y + f0.z*f0.z + f0.w*f0.w
                 + f1.x*f1.x + f1.y*f1.y + f1.z*f1.z + f1.w*f1.w
                 + f2.x*f2.x + f2.y*f2.y + f2.z*f2.z + f2.w*f2.w
                 + f3.x*f3.x + f3.y*f3.y + f3.z*f3.z + f3.w*f3.w;
            i32x4 v = { (int)pack4(f0.x, f0.y, f0.z, f0.w),
                        (int)pack4(f1.x, f1.y, f1.z, f1.w),
                        (int)pack4(f2.x, f2.y, f2.z, f2.w),
                        (int)pack4(f3.x, f3.y, f3.z, f3.w) };
            const int kt = 2 * q4 + (c >> 2), sl = c & 3;
            *(i32x4*)&As[kt * 4096 + r * 64 + (sl ^ rsw) * 16] = v;
        }
        nrm += __shfl_xor(nrm, 1);
        nrm += __shfl_xor(nrm, 2);                // lanes of a row-quartet
    }
    __syncthreads();   // As visible to all; drains B(0),B(1) too

    i32x4 acc[4][4];
    #pragma unroll
    for (int m = 0; m < 4; ++m)
        #pragma unroll
        for (int n = 0; n < 4; ++n) acc[m][n] = (i32x4)0;
    uint32_t runKey[4][4];
    #pragma unroll
    for (int m = 0; m < 4; ++m)
        #pragma unroll
        for (int rr = 0; rr < 4; ++rr) runKey[m][rr] = 0xFFFFFFFFu;

    const int fq = (kg ^ ((lr >> 1) & 3)) * 16;   // swizzled read slot (bytes)
    const char* bR = Bs + wave * 12288;

    for (int ctp = 0; ctp < 4; ++ctp) {
        #pragma unroll
        for (int kt = 0; kt < 8; ++kt) {
            const int s = ctp * 8 + kt;
            const int buf = s % 3;
            i32x4 aF[4], bF[4];
            #pragma unroll
            for (int m = 0; m < 4; ++m)
                aF[m] = *(const i32x4*)&As[kt * 4096 + (m * 16 + lr) * 64 + fq];
            #pragma unroll
            for (int n = 0; n < 4; ++n)
                bF[n] = *(const i32x4*)&bR[buf * 4096 + (n * 16 + lr) * 64 + fq];
            if (s + 2 < 32) STAGE_B(s + 2);       // depth-2, wave-private
            #pragma unroll
            for (int m = 0; m < 4; ++m)
                #pragma unroll
                for (int n = 0; n < 4; ++n)
                    acc[m][n] = __builtin_amdgcn_mfma_i32_16x16x64_i8(
                        aF[m], bF[n], acc[m][n], 0, 0, 0);
            if (s + 2 < 32)   asm volatile("s_waitcnt vmcnt(4)" ::: "memory");
            else if (s == 30) asm volatile("s_waitcnt vmcnt(0)" ::: "memory");
        }
        // ct-pair complete: fold scores into running packed keys
        #pragma unroll
        for (int n = 0; n < 4; ++n) {
            const int wcol = colW + ctp * 64 + n * 16 + lr;
            const float wn = wnorm[wcol];
            #pragma unroll
            for (int m = 0; m < 4; ++m)
                #pragma unroll
                for (int rr = 0; rr < 4; ++rr) {
                    float sc = wn - (float)acc[m][n][rr] * 0.001953125f;
                    uint32_t u = __float_as_uint(sc);
                    u = (u & 0x80000000u) ? ~u : (u | 0x80000000u);
                    runKey[m][rr] = min(runKey[m][rr],
                                        (u & ~1023u) | (uint32_t)wcol);
                }
        }
        #pragma unroll
        for (int m = 0; m < 4; ++m)
            #pragma unroll
            for (int n = 0; n < 4; ++n) acc[m][n] = (i32x4)0;
    }
#undef STAGE_B

    // ---- per-wave 16-lane col reduce -> kbuf; park xnorm in dead Bs ----
    uint32_t* kbuf = (uint32_t*)(Bs + wave * 12288);   // own region, loop done
    #pragma unroll
    for (int m = 0; m < 4; ++m)
        #pragma unroll
        for (int rr = 0; rr < 4; ++rr) {
            uint32_t k = runKey[m][rr];
            #pragma unroll
            for (int d = 1; d < 16; d <<= 1)
                k = min(k, (uint32_t)__shfl_xor((int)k, d));
            if (lr == 0) kbuf[m * 16 + kg * 4 + rr] = k;
        }
    float* xnS = (float*)(Bs + 48896);   // dead space, clear of all kbufs
    if ((tid & 3) == 0) xnS[r] = nrm;
    __syncthreads();

    // ---- wave 0: merge 4 waves' keys per row, add exact xnorm, block sum ----
    if (wave == 0) {
        const uint32_t* k0 = (const uint32_t*)(Bs);
        uint32_t k = min(min(k0[lane], k0[3072 + lane]),
                         min(k0[6144 + lane], k0[9216 + lane]));
        uint32_t sb = k & ~1023u;
        float sc = (sb & 0x80000000u) ? __uint_as_float(sb ^ 0x80000000u)
                                      : __uint_as_float(~sb);
        float v = xnS[lane] + sc;
        #pragma unroll
        for (int d = 1; d < 64; d <<= 1) v += __shfl_xor(v, d);
        if (lane == 0) partial[bid] = v;
    }
}

// ---------------- K2: final mean over 512 partials (double accum) ----------------
__global__ void __launch_bounds__(256)
finalize(const float* __restrict__ partial, float* __restrict__ out) {
    __shared__ double sm[256];
    sm[threadIdx.x] = (double)partial[threadIdx.x]
                    + (double)partial[threadIdx.x + 256];
    __syncthreads();
    for (int st = 128; st > 0; st >>= 1) {
        if (threadIdx.x < st) sm[threadIdx.x] += sm[threadIdx.x + st];
        __syncthreads();
    }
    if (threadIdx.x == 0)
        out[0] = (float)(sm[0] / (double)((size_t)N_ROWS * DIM));
}

extern "C" void kernel_launch(void* const* d_in, const int* in_sizes, int n_in,
                              void* d_out, int out_size, void* d_ws, size_t ws_size,
                              hipStream_t stream) {
    const float* X = (const float*)d_in[0];   // [32768][512]
    const float* W = (const float*)d_in[1];   // [1024][512]
    char* ws = (char*)d_ws;
    char*   Wq      = ws;                            // 512 KB @ 0
    float*  wnorm   = (float*)(ws + 524288);         // 4 KB
    float*  partial = (float*)(ws + 528384);         // 2 KB
    float*  out     = (float*)d_out;

    convertW<<<N_CODES / 4, 256, 0, stream>>>(W, Wq, wnorm);
    gemm_argmin<<<512, 256, 0, stream>>>(X, Wq, wnorm, partial);
    finalize<<<1, 256, 0, stream>>>(partial, out);
}